// Round 13
// baseline (208.450 us; speedup 1.0000x reference)
//
#include <hip/hip_runtime.h>
#include <stdint.h>

typedef uint32_t u32;
typedef unsigned long long u64;

#define NB 8
#define NPER 4000
#define NC 91
#define NCLS 90
#define NDET 100
#define CHUNKS 64
#define RPB 63         // rows per k_score block; 64*63=4032 covers 4000 w/ guard
#define LBIN 16        // LDS staging per class per chunk (avg ~1.6 used)
#define CCAP 63        // per-(chunk,class) global bin cap == rows/chunk (EXACT)
#define BINCAP 512     // per-(image,class) NMS pool clamp (avg ~103)
#define NWRD 8         // bitmask words = BINCAP/64
#define MPAD 9         // matrix row stride in u64 (9 breaks the 64B bank cycle)
#define SURVCAP 9216   // fixed survivor slots: 90 classes x 100 + pad
#define NSFIX (NCLS * NDET)  // 9000 real slots
#define FKCAP 1024     // k_top compacted pool (100 + score ties)
#define VPT 36         // k_top values/thread = SURVCAP/256

// ---------------------------------------------------------------- decode ----
// bit-identical to reference op order (verified absmax 0.0 in R1-R12)
__device__ __forceinline__ float4 decode_clip(float4 rel, float w, float h,
                                              float cx, float cy, float W, float H) {
  const float XCLIP = 4.135166556742356f;  // log(1000/16)
  float dx = rel.x / 10.0f;
  float dy = rel.y / 10.0f;
  float dw = fminf(rel.z / 5.0f, XCLIP);
  float dh = fminf(rel.w / 5.0f, XCLIP);
  float qcx = dx * w + cx;
  float qcy = dy * h + cy;
  float qw = expf(dw) * w;
  float qh = expf(dh) * h;
  float x1 = qcx - 0.5f * qw, y1 = qcy - 0.5f * qh;
  float x2 = qcx + 0.5f * qw, y2 = qcy + 0.5f * qh;
  x1 = fminf(fmaxf(x1, 0.0f), W);
  x2 = fminf(fmaxf(x2, 0.0f), W);
  y1 = fminf(fmaxf(y1, 0.0f), H);
  y2 = fminf(fmaxf(y2, 0.0f), H);
  return make_float4(x1, y1, x2, y2);
}

// ---------------------------------------------------------------- k_score ---
__device__ __forceinline__ void emit_row(int r, int rl, int lane, float sA, float sB,
    float W, float H, const float4* __restrict__ props4, const float4* __restrict__ breg4,
    u32* s_cnt, u64 (*s_key)[LBIN], float4 (*s_box)[LBIN],
    size_t chbase, u64* __restrict__ bins_key, float4* __restrict__ bins_box) {
  bool eA_ok = (lane >= 1) && (sA > 0.05f);
  bool eB_ok = (lane < NC - 64) && (sB > 0.05f);
  if (!(eA_ok || eB_ok)) return;
  float4 p = props4[r];
  float w = p.z - p.x, h = p.w - p.y;
  float cx = p.x + 0.5f * w, cy = p.y + 0.5f * h;
  if (eA_ok) {
    float4 raw = decode_clip(breg4[(size_t)r * NC + lane], w, h, cx, cy, W, H);
    if (((raw.z - raw.x) >= 0.01f) && ((raw.w - raw.y) >= 0.01f)) {
      int ci = lane - 1;
      u32 orig = (u32)(rl * NCLS + ci);
      u64 key = ((u64)__float_as_uint(sA) << 22) | (u64)(0x3FFFFFu - orig);
      u32 lp = atomicAdd(&s_cnt[ci], 1u);  // LDS only
      if (lp < LBIN) { s_key[ci][lp] = key; s_box[ci][lp] = raw; }
      else if (lp < CCAP) {  // block-private global slot, no atomic
        size_t o = (chbase + ci) * CCAP + lp;
        bins_key[o] = key; bins_box[o] = raw;
      }
    }
  }
  if (eB_ok) {
    float4 raw = decode_clip(breg4[(size_t)r * NC + 64 + lane], w, h, cx, cy, W, H);
    if (((raw.z - raw.x) >= 0.01f) && ((raw.w - raw.y) >= 0.01f)) {
      int ci = 63 + lane;
      u32 orig = (u32)(rl * NCLS + ci);
      u64 key = ((u64)__float_as_uint(sB) << 22) | (u64)(0x3FFFFFu - orig);
      u32 lp = atomicAdd(&s_cnt[ci], 1u);
      if (lp < LBIN) { s_key[ci][lp] = key; s_box[ci][lp] = raw; }
      else if (lp < CCAP) {
        size_t o = (chbase + ci) * CCAP + lp;
        bins_key[o] = key; bins_box[o] = raw;
      }
    }
  }
}

// Front-end: softmax + decode + filter. TWO rows per wave iteration with
// interleaved (independent) shfl-reduce chains -- per-row op order is
// bit-identical; the 12-deep dependent shfl latency overlapped 2-wide.
// Block-private bins, no global atomics.
__global__ __launch_bounds__(1024) void k_score(const float* __restrict__ logits,
    const float* __restrict__ boxreg, const float* __restrict__ props,
    const int* __restrict__ dh, const int* __restrict__ dw,
    u32* cnt_g, u64* bins_key, float4* bins_box) {
  __shared__ u64 s_key[NCLS][LBIN];
  __shared__ float4 s_box[NCLS][LBIN];
  __shared__ u32 s_cnt[NCLS];
  int tid = threadIdx.x;
  int b = blockIdx.x / CHUNKS;
  int chunk = blockIdx.x % CHUNKS;
  int wave = tid >> 6, lane = tid & 63;
  if (tid < NCLS) s_cnt[tid] = 0u;
  __syncthreads();

  float H = (float)dh[0], W = (float)dw[0];
  const float4* props4 = (const float4*)props;
  const float4* breg4 = (const float4*)boxreg;
  size_t chbase = ((size_t)(b * CHUNKS + chunk)) * NCLS;  // *CCAP for bins

  for (int rloc = wave; rloc < RPB; rloc += 32) {
    int rloc1 = rloc + 16;
    int rl0 = chunk * RPB + rloc;
    int rl1 = chunk * RPB + rloc1;
    bool v0 = (rl0 < NPER);
    bool v1 = (rloc1 < RPB) && (rl1 < NPER);
    int r0 = b * NPER + (v0 ? rl0 : 0);
    int r1 = b * NPER + (v1 ? rl1 : 0);
    const float* l0 = logits + (size_t)r0 * NC;
    const float* l1 = logits + (size_t)r1 * NC;
    float xA0 = l0[lane];
    float xA1 = l1[lane];
    float xB0 = (lane < NC - 64) ? l0[64 + lane] : -3.0e38f;
    float xB1 = (lane < NC - 64) ? l1[64 + lane] : -3.0e38f;
    float mx0 = fmaxf(xA0, xB0);
    float mx1 = fmaxf(xA1, xB1);
    for (int o = 32; o; o >>= 1) {
      mx0 = fmaxf(mx0, __shfl_xor(mx0, o));
      mx1 = fmaxf(mx1, __shfl_xor(mx1, o));
    }
    float eA0 = expf(xA0 - mx0);
    float eA1 = expf(xA1 - mx1);
    float eB0 = (lane < NC - 64) ? expf(xB0 - mx0) : 0.0f;
    float eB1 = (lane < NC - 64) ? expf(xB1 - mx1) : 0.0f;
    float sm0 = eA0 + eB0;
    float sm1 = eA1 + eB1;
    for (int o = 32; o; o >>= 1) {
      sm0 += __shfl_xor(sm0, o);
      sm1 += __shfl_xor(sm1, o);
    }
    if (v0) emit_row(r0, rl0, lane, eA0 / sm0, eB0 / sm0, W, H, props4, breg4,
                     s_cnt, s_key, s_box, chbase, bins_key, bins_box);
    if (v1) emit_row(r1, rl1, lane, eA1 / sm1, eB1 / sm1, W, H, props4, breg4,
                     s_cnt, s_key, s_box, chbase, bins_key, bins_box);
  }
  __syncthreads();
  if (tid < NCLS) cnt_g[chbase + tid] = s_cnt[tid];  // plain store
  for (int idx = tid; idx < NCLS * LBIN; idx += 1024) {  // cooperative LDS flush
    int ci = idx / LBIN, j = idx % LBIN;
    if ((u32)j < s_cnt[ci]) {
      size_t o = (chbase + ci) * CCAP + (u32)j;
      bins_key[o] = s_key[ci][j];
      bins_box[o] = s_box[ci][j];
    }
  }
}

// Per-(image,class) greedy NMS via SUPPRESSION BIT-MATRIX (== greedy:
// sweep in rank order; suppressed items never apply their masks; early
// exit at 100 kept yields the same first-100 set). Replaces R12's serial
// ballot loop (~100 x ~150cy dependent readlane chain) with:
//   matrix build -- fully parallel, wave-uniform j-loop (LDS broadcasts)
//   sweep -- ~n-iteration register/LDS-broadcast loop, all lanes lockstep
//   compact -- popcount prefix on register bitmask words
__global__ __launch_bounds__(256) void k_nms_class(const u32* __restrict__ cnt_g,
    const u64* __restrict__ bins_key, const float4* __restrict__ bins_box,
    u64* skey, float4* sbox, const int* __restrict__ dh, const int* __restrict__ dw) {
  __shared__ u64 ks[BINCAP];                 // rank-sorted keys (desc)
  __shared__ float4 boxs[BINCAP];            // rank-sorted raw boxes
  __shared__ __align__(16) char ovl[BINCAP * MPAD * 8];  // staging | matrix
  __shared__ u32 s_off[64];
  __shared__ u32 s_c[64];
  __shared__ u32 s_n;
  u64* ku = (u64*)ovl;                       // phase A: unsorted keys (4 KB)
  float4* boxu = (float4*)(ovl + BINCAP * 8);  // phase A: unsorted boxes (8 KB)
  u64* mat = (u64*)ovl;                      // phase B: mat[i*MPAD + w] (36 KB)

  int b = blockIdx.x / NCLS;
  int ci = blockIdx.x % NCLS;
  int tid = threadIdx.x;
  u64* outk = skey + (size_t)b * SURVCAP + (size_t)ci * NDET;
  float4* outb = sbox + (size_t)b * SURVCAP + (size_t)ci * NDET;

  if (tid < 64) {  // lane == chunk: counts + wave prefix scan
    u32 c = cnt_g[((size_t)(b * CHUNKS + tid)) * NCLS + ci];
    if (c > CCAP) c = CCAP;
    s_c[tid] = c;
    u32 inc = c;
    for (int o = 1; o < 64; o <<= 1) {
      u32 v = __shfl_up(inc, o);
      if (tid >= o) inc += v;
    }
    s_off[tid] = inc - c;
    if (tid == 63) s_n = (inc > BINCAP) ? BINCAP : inc;
  }
  __syncthreads();
  int n = (int)s_n;
  if (n <= 0) {
    for (int i = tid; i < NDET; i += 256) outk[i] = 0ull;
    return;
  }
  {  // cooperative gather: 4 threads per chunk
    int chunk = tid & 63, start = tid >> 6;
    u32 cc = s_c[chunk], of = s_off[chunk];
    size_t src = (((size_t)(b * CHUNKS + chunk)) * NCLS + ci) * CCAP;
    for (u32 i = (u32)start; i < cc; i += 4) {
      u32 d = of + i;
      if (d < (u32)BINCAP) { ku[d] = bins_key[src + i]; boxu[d] = bins_box[src + i]; }
    }
  }
  __syncthreads();
  for (int i = tid; i < n; i += 256) {  // rank sort: broadcast reads, no barriers
    u64 ki = ku[i];
    u32 rank = 0;
    int j = 0;
    for (; j + 4 <= n; j += 4) {
      rank += (ku[j] > ki) ? 1u : 0u;
      rank += (ku[j + 1] > ki) ? 1u : 0u;
      rank += (ku[j + 2] > ki) ? 1u : 0u;
      rank += (ku[j + 3] > ki) ? 1u : 0u;
    }
    for (; j < n; ++j) rank += (ku[j] > ki) ? 1u : 0u;
    ks[rank] = ki;
    boxs[rank] = boxu[i];
  }
  __syncthreads();  // staging dead; overlay becomes the matrix

  float H = (float)dh[0], W = (float)dw[0];
  float loff = (fmaxf(H, W) + 1.0f) * (float)(ci + 1);

  // ---- suppression matrix: row i = bits of j>i with IoU>0.5 ----
  for (int i = tid; i < n; i += 256) {
    float4 bi = boxs[i];
    float4 Bi = make_float4(bi.x + loff, bi.y + loff, bi.z + loff, bi.w + loff);
    float ai = (Bi.z - Bi.x) * (Bi.w - Bi.y);
    u64 w[NWRD];
#pragma unroll
    for (int t = 0; t < NWRD; ++t) w[t] = 0ull;
    for (int j = 0; j < n; ++j) {        // j uniform -> boxs[j] broadcast
      float4 bj = boxs[j];
      float4 Bj = make_float4(bj.x + loff, bj.y + loff, bj.z + loff, bj.w + loff);
      float aj = (Bj.z - Bj.x) * (Bj.w - Bj.y);
      float ix1 = fmaxf(Bi.x, Bj.x), iy1 = fmaxf(Bi.y, Bj.y);
      float ix2 = fminf(Bi.z, Bj.z), iy2 = fminf(Bi.w, Bj.w);
      float inter = fmaxf(ix2 - ix1, 0.0f) * fmaxf(iy2 - iy1, 0.0f);
      float iou = inter / fmaxf(ai + aj - inter, 1e-9f);
      if (j > i && iou > 0.5f) w[j >> 6] |= (1ull << (j & 63));
    }
#pragma unroll
    for (int t = 0; t < NWRD; ++t) mat[i * MPAD + t] = w[t];
  }
  __syncthreads();
  if (tid >= 64) return;  // wave 0 finishes barrier-free

  // ---- sweep (all 64 lanes lockstep; mat reads broadcast; rem/kb in regs) --
  u64 rem[NWRD], kb[NWRD];
#pragma unroll
  for (int t = 0; t < NWRD; ++t) { rem[t] = 0ull; kb[t] = 0ull; }
  int kept = 0;
  for (int i = 0; i < n; ++i) {
    if (!((rem[i >> 6] >> (i & 63)) & 1ull)) {
      kb[i >> 6] |= (1ull << (i & 63));
      ++kept;
#pragma unroll
      for (int t = 0; t < NWRD; ++t) rem[t] |= mat[i * MPAD + t];
      if (kept == NDET) break;
    }
  }
  // ---- compact: pos = popcount of kept bits before i (kb identical/lane) --
  int lane = tid;
  for (int i = lane; i < n; i += 64) {
    if ((kb[i >> 6] >> (i & 63)) & 1ull) {
      int wi = i >> 6;
      u32 pos = 0;
      for (int t = 0; t < wi; ++t) pos += (u32)__popcll(kb[t]);
      u64 low = (i & 63) ? (kb[wi] & ((1ull << (i & 63)) - 1ull)) : 0ull;
      pos += (u32)__popcll(low);
      outk[pos] = ks[i];
      outb[pos] = boxs[i];
    }
  }
  for (int i2 = kept + lane; i2 < NDET; i2 += 64) outk[i2] = 0ull;  // zero-pad
}

// Per-image exact top-NDET over the fixed 9000 survivor slots (key==0 =
// empty, never selectable). Register-resident bisection on (0.05,1] bits
// for the 100th-largest score T; compact >T plus ==T ties; wave-0 rank
// sort (keys unique) into the 100 outputs.
__global__ __launch_bounds__(256) void k_top(const u64* __restrict__ skey,
    const float4* __restrict__ sbox, float* out) {
  __shared__ u32 ssc[SURVCAP];
  __shared__ u32 s_red[4];
  __shared__ u32 s_cnt[2];
  __shared__ u64 fk[FKCAP];
  __shared__ u32 fs[FKCAP];
  __shared__ u64 okey[NDET];
  __shared__ u32 osrc[NDET];

  int b = blockIdx.x;
  int tid = threadIdx.x;
  const u64* kb = skey + (size_t)b * SURVCAP;

  u32 sc[VPT];
#pragma unroll
  for (int v = 0; v < VPT; ++v) {
    u32 j = (u32)tid + (u32)v * 256u;
    u32 s = 0u;
    if (j < NSFIX) s = (u32)(kb[j] >> 22);
    sc[v] = s;
    ssc[j] = s;
  }
  if (tid == 0) { s_cnt[0] = 0; s_cnt[1] = 0; }
  __syncthreads();

  // minimal x with count(s > x) < NDET; scores in (0.05, 1]
  u32 lo = 0x3D4CCCCEu, hi = 0x3F800001u;
  while (lo < hi) {
    u32 mid = lo + ((hi - lo) >> 1);
    u32 c = 0;
#pragma unroll
    for (int v = 0; v < VPT; ++v) c += (sc[v] > mid) ? 1u : 0u;
    for (int o = 32; o; o >>= 1) c += __shfl_xor(c, o);
    if ((tid & 63) == 0) s_red[tid >> 6] = c;
    __syncthreads();
    u32 totc = s_red[0] + s_red[1] + s_red[2] + s_red[3];
    __syncthreads();
    if (totc < NDET) hi = mid; else lo = mid + 1;
  }
  u32 T = lo;
  __syncthreads();

  for (u32 j = tid; j < NSFIX; j += 256) {
    if (ssc[j] > T) {
      u32 p = atomicAdd(&s_cnt[0], 1u);
      if (p < FKCAP) { fk[p] = kb[j]; fs[p] = j; }
    }
  }
  __syncthreads();
  if (tid == 0) s_cnt[1] = s_cnt[0];
  __syncthreads();
  for (u32 j = tid; j < NSFIX; j += 256) {  // ==T ties; order fixed by rank sort
    if (ssc[j] == T) {
      u32 p = atomicAdd(&s_cnt[1], 1u);
      if (p < FKCAP) { fk[p] = kb[j]; fs[p] = j; }
    }
  }
  __syncthreads();
  u32 tot = s_cnt[1];
  if (tot > FKCAP) tot = FKCAP;
  if (tid >= 64) return;  // wave 0 finishes barrier-free

  for (int i = tid; i < NDET; i += 64) okey[i] = 0ull;
  for (int i = tid; i < (int)tot; i += 64) {  // rank sort (keys unique)
    u64 ki = fk[i];
    u32 rank = 0;
    for (int j = 0; j < (int)tot; ++j) rank += (fk[j] > ki) ? 1u : 0u;
    if (rank < NDET) { okey[rank] = ki; osrc[rank] = fs[i]; }
  }
  // boxes[3200] | scores[800] | labels[800] | keep[800]
  for (int i = tid; i < NDET; i += 64) {
    u64 key = okey[i];
    float b0 = 0.f, b1 = 0.f, b2 = 0.f, b3 = 0.f, sc2 = 0.f, lb = 0.f, kp = 0.f;
    if (key) {
      float4 bx = sbox[(size_t)b * SURVCAP + osrc[i]];
      b0 = bx.x; b1 = bx.y; b2 = bx.z; b3 = bx.w;
      sc2 = __uint_as_float((u32)(key >> 22));
      u32 orig = 0x3FFFFFu - (u32)(key & 0x3FFFFFu);
      lb = (float)(orig % NCLS + 1u);
      kp = 1.0f;
    }
    float* ob = out + ((size_t)b * NDET + i) * 4;
    ob[0] = b0; ob[1] = b1; ob[2] = b2; ob[3] = b3;
    out[NB * NDET * 4 + b * NDET + i] = sc2;
    out[NB * NDET * 5 + b * NDET + i] = lb;
    out[NB * NDET * 6 + b * NDET + i] = kp;
  }
}

// ---------------------------------------------------------------- launch ----
extern "C" void kernel_launch(void* const* d_in, const int* in_sizes, int n_in,
                              void* d_out, int out_size, void* d_ws, size_t ws_size,
                              hipStream_t stream) {
  const float* logits = (const float*)d_in[0];
  const float* boxreg = (const float*)d_in[1];
  const float* props  = (const float*)d_in[2];
  const int* dh = (const int*)d_in[3];
  const int* dw = (const int*)d_in[4];
  float* out = (float*)d_out;

  char* ws = (char*)d_ws;
  u32* cnt_g = (u32*)ws;                                      // 8*64*90 u32 = 180 KiB
  char* p0 = ws + (((size_t)NB * CHUNKS * NCLS * 4 + 255) & ~(size_t)255);
  u64* bins_key = (u64*)p0;                                   // 8*64*90*63*8  = 23.2 MB
  char* p1 = p0 + (size_t)NB * CHUNKS * NCLS * CCAP * 8;
  float4* bins_box = (float4*)p1;                             // 8*64*90*63*16 = 46.4 MB
  char* p2 = p1 + (size_t)NB * CHUNKS * NCLS * CCAP * 16;
  u64* skey = (u64*)p2;                                       // 8*9216*8 = 590 KB
  float4* sbox = (float4*)(p2 + (size_t)NB * SURVCAP * 8);    // 8*9216*16 = 1.18 MB
  (void)ws_size;

  k_score<<<NB * CHUNKS, 1024, 0, stream>>>(logits, boxreg, props, dh, dw,
                                            cnt_g, bins_key, bins_box);
  k_nms_class<<<NB * NCLS, 256, 0, stream>>>(cnt_g, bins_key, bins_box,
                                             skey, sbox, dh, dw);
  k_top<<<NB, 256, 0, stream>>>(skey, sbox, out);
}

// Round 14
// 170.202 us; speedup vs baseline: 1.2247x; 1.2247x over previous
//
#include <hip/hip_runtime.h>
#include <stdint.h>

typedef uint32_t u32;
typedef unsigned long long u64;

#define NB 8
#define NPER 4000
#define NC 91
#define NCLS 90
#define NDET 100
#define CHUNKS 64
#define RPB 63         // rows per k_score block; 64*63=4032 covers 4000 w/ guard
#define LBIN 16        // LDS staging per class per chunk (avg ~1.6 used)
#define CCAP 63        // per-(chunk,class) global bin cap == rows/chunk (EXACT)
#define BINCAP 512     // per-(image,class) NMS pool clamp (avg ~103)
#define SURVCAP 9216   // fixed survivor slots: 90 classes x 100 + pad
#define NSFIX (NCLS * NDET)  // 9000 real slots
#define FKCAP 1024     // k_top compacted pool (100 + score ties)
#define VPT 36         // k_top values/thread = SURVCAP/256

// ---------------------------------------------------------------- decode ----
// bit-identical to reference op order (verified absmax 0.0 in R1-R13)
__device__ __forceinline__ float4 decode_clip(float4 rel, float w, float h,
                                              float cx, float cy, float W, float H) {
  const float XCLIP = 4.135166556742356f;  // log(1000/16)
  float dx = rel.x / 10.0f;
  float dy = rel.y / 10.0f;
  float dw = fminf(rel.z / 5.0f, XCLIP);
  float dh = fminf(rel.w / 5.0f, XCLIP);
  float qcx = dx * w + cx;
  float qcy = dy * h + cy;
  float qw = expf(dw) * w;
  float qh = expf(dh) * h;
  float x1 = qcx - 0.5f * qw, y1 = qcy - 0.5f * qh;
  float x2 = qcx + 0.5f * qw, y2 = qcy + 0.5f * qh;
  x1 = fminf(fmaxf(x1, 0.0f), W);
  x2 = fminf(fmaxf(x2, 0.0f), W);
  y1 = fminf(fmaxf(y1, 0.0f), H);
  y2 = fminf(fmaxf(y2, 0.0f), H);
  return make_float4(x1, y1, x2, y2);
}

__device__ __forceinline__ float rdlane(float v, int sl) {
  return __int_as_float(__builtin_amdgcn_readlane(__float_as_int(v), sl));
}

// ---------------------------------------------------------------- k_score ---
__device__ __forceinline__ void emit_row(int r, int rl, int lane, float sA, float sB,
    float W, float H, const float4* __restrict__ props4, const float4* __restrict__ breg4,
    u32* s_cnt, u64 (*s_key)[LBIN], float4 (*s_box)[LBIN],
    size_t chbase, u64* __restrict__ bins_key, float4* __restrict__ bins_box) {
  bool eA_ok = (lane >= 1) && (sA > 0.05f);
  bool eB_ok = (lane < NC - 64) && (sB > 0.05f);
  if (!(eA_ok || eB_ok)) return;
  float4 p = props4[r];
  float w = p.z - p.x, h = p.w - p.y;
  float cx = p.x + 0.5f * w, cy = p.y + 0.5f * h;
  if (eA_ok) {
    float4 raw = decode_clip(breg4[(size_t)r * NC + lane], w, h, cx, cy, W, H);
    if (((raw.z - raw.x) >= 0.01f) && ((raw.w - raw.y) >= 0.01f)) {
      int ci = lane - 1;
      u32 orig = (u32)(rl * NCLS + ci);
      u64 key = ((u64)__float_as_uint(sA) << 22) | (u64)(0x3FFFFFu - orig);
      u32 lp = atomicAdd(&s_cnt[ci], 1u);  // LDS only
      if (lp < LBIN) { s_key[ci][lp] = key; s_box[ci][lp] = raw; }
      else if (lp < CCAP) {  // block-private global slot, no atomic
        size_t o = (chbase + ci) * CCAP + lp;
        bins_key[o] = key; bins_box[o] = raw;
      }
    }
  }
  if (eB_ok) {
    float4 raw = decode_clip(breg4[(size_t)r * NC + 64 + lane], w, h, cx, cy, W, H);
    if (((raw.z - raw.x) >= 0.01f) && ((raw.w - raw.y) >= 0.01f)) {
      int ci = 63 + lane;
      u32 orig = (u32)(rl * NCLS + ci);
      u64 key = ((u64)__float_as_uint(sB) << 22) | (u64)(0x3FFFFFu - orig);
      u32 lp = atomicAdd(&s_cnt[ci], 1u);
      if (lp < LBIN) { s_key[ci][lp] = key; s_box[ci][lp] = raw; }
      else if (lp < CCAP) {
        size_t o = (chbase + ci) * CCAP + lp;
        bins_key[o] = key; bins_box[o] = raw;
      }
    }
  }
}

// Front-end: softmax + decode + filter. TWO rows per wave iteration with
// interleaved (independent) shfl-reduce chains -- per-row op order is
// bit-identical (same xor sequence / exp / div); the 12-deep dependent
// shfl latency is overlapped 2-wide. Block-private bins, no global atomics.
__global__ __launch_bounds__(1024) void k_score(const float* __restrict__ logits,
    const float* __restrict__ boxreg, const float* __restrict__ props,
    const int* __restrict__ dh, const int* __restrict__ dw,
    u32* cnt_g, u64* bins_key, float4* bins_box) {
  __shared__ u64 s_key[NCLS][LBIN];
  __shared__ float4 s_box[NCLS][LBIN];
  __shared__ u32 s_cnt[NCLS];
  int tid = threadIdx.x;
  int b = blockIdx.x / CHUNKS;
  int chunk = blockIdx.x % CHUNKS;
  int wave = tid >> 6, lane = tid & 63;
  if (tid < NCLS) s_cnt[tid] = 0u;
  __syncthreads();

  float H = (float)dh[0], W = (float)dw[0];
  const float4* props4 = (const float4*)props;
  const float4* breg4 = (const float4*)boxreg;
  size_t chbase = ((size_t)(b * CHUNKS + chunk)) * NCLS;  // *CCAP for bins

  for (int rloc = wave; rloc < RPB; rloc += 32) {
    int rloc1 = rloc + 16;
    int rl0 = chunk * RPB + rloc;
    int rl1 = chunk * RPB + rloc1;
    bool v0 = (rl0 < NPER);
    bool v1 = (rloc1 < RPB) && (rl1 < NPER);
    int r0 = b * NPER + (v0 ? rl0 : 0);
    int r1 = b * NPER + (v1 ? rl1 : 0);
    const float* l0 = logits + (size_t)r0 * NC;
    const float* l1 = logits + (size_t)r1 * NC;
    float xA0 = l0[lane];
    float xA1 = l1[lane];
    float xB0 = (lane < NC - 64) ? l0[64 + lane] : -3.0e38f;
    float xB1 = (lane < NC - 64) ? l1[64 + lane] : -3.0e38f;
    float mx0 = fmaxf(xA0, xB0);
    float mx1 = fmaxf(xA1, xB1);
    for (int o = 32; o; o >>= 1) {
      mx0 = fmaxf(mx0, __shfl_xor(mx0, o));
      mx1 = fmaxf(mx1, __shfl_xor(mx1, o));
    }
    float eA0 = expf(xA0 - mx0);
    float eA1 = expf(xA1 - mx1);
    float eB0 = (lane < NC - 64) ? expf(xB0 - mx0) : 0.0f;
    float eB1 = (lane < NC - 64) ? expf(xB1 - mx1) : 0.0f;
    float sm0 = eA0 + eB0;
    float sm1 = eA1 + eB1;
    for (int o = 32; o; o >>= 1) {
      sm0 += __shfl_xor(sm0, o);
      sm1 += __shfl_xor(sm1, o);
    }
    if (v0) emit_row(r0, rl0, lane, eA0 / sm0, eB0 / sm0, W, H, props4, breg4,
                     s_cnt, s_key, s_box, chbase, bins_key, bins_box);
    if (v1) emit_row(r1, rl1, lane, eA1 / sm1, eB1 / sm1, W, H, props4, breg4,
                     s_cnt, s_key, s_box, chbase, bins_key, bins_box);
  }
  __syncthreads();
  if (tid < NCLS) cnt_g[chbase + tid] = s_cnt[tid];  // plain store
  for (int idx = tid; idx < NCLS * LBIN; idx += 1024) {  // cooperative LDS flush
    int ci = idx / LBIN, j = idx % LBIN;
    if ((u32)j < s_cnt[ci]) {
      size_t o = (chbase + ci) * CCAP + (u32)j;
      bins_key[o] = s_key[ci][j];
      bins_box[o] = s_box[ci][j];
    }
  }
}

// Per-(image,class) greedy NMS (R12 configuration -- the resource-light
// variant: 20 VGPR / 28 KB LDS / 5 blocks-per-CU headroom. R13's bit-matrix
// variant regressed to 76us via 68 VGPR + 50 KB LDS + unpipelined O(n^2)
// build; R11's fused variant regressed via LDS/VGPR inflation + fences).
// Gather 4 threads/chunk, rank sort (exact: keys unique), wave-0
// ballot-greedy with readlane broadcast, fixed zero-padded survivor slots.
__global__ __launch_bounds__(256) void k_nms_class(const u32* __restrict__ cnt_g,
    const u64* __restrict__ bins_key, const float4* __restrict__ bins_box,
    u64* skey, float4* sbox, const int* __restrict__ dh, const int* __restrict__ dw) {
  __shared__ u64 k[BINCAP];       // unsorted keys
  __shared__ float4 boxu[BINCAP]; // unsorted boxes
  __shared__ u64 ks[BINCAP];      // rank-sorted keys (desc)
  __shared__ float4 boxs[BINCAP]; // rank-sorted boxes
  __shared__ float4 s_sb[NDET];   // survivor offset boxes (IoU space)
  __shared__ float s_sa[NDET];
  __shared__ u64 s_sk[NDET];
  __shared__ u32 s_sid[NDET];
  __shared__ u32 s_off[64];
  __shared__ u32 s_c[64];
  __shared__ u32 s_n;

  int b = blockIdx.x / NCLS;
  int ci = blockIdx.x % NCLS;
  int tid = threadIdx.x;
  u64* outk = skey + (size_t)b * SURVCAP + (size_t)ci * NDET;
  float4* outb = sbox + (size_t)b * SURVCAP + (size_t)ci * NDET;

  if (tid < 64) {  // lane == chunk: counts + wave prefix scan
    u32 c = cnt_g[((size_t)(b * CHUNKS + tid)) * NCLS + ci];
    if (c > CCAP) c = CCAP;
    s_c[tid] = c;
    u32 inc = c;
    for (int o = 1; o < 64; o <<= 1) {
      u32 v = __shfl_up(inc, o);
      if (tid >= o) inc += v;
    }
    s_off[tid] = inc - c;
    if (tid == 63) s_n = (inc > BINCAP) ? BINCAP : inc;
  }
  __syncthreads();
  int n = (int)s_n;
  if (n <= 0) {
    for (int i = tid; i < NDET; i += 256) outk[i] = 0ull;
    return;
  }
  {  // cooperative gather: 4 threads per chunk
    int chunk = tid & 63, start = tid >> 6;
    u32 cc = s_c[chunk], of = s_off[chunk];
    size_t src = (((size_t)(b * CHUNKS + chunk)) * NCLS + ci) * CCAP;
    for (u32 i = (u32)start; i < cc; i += 4) {
      u32 d = of + i;
      if (d < (u32)BINCAP) { k[d] = bins_key[src + i]; boxu[d] = bins_box[src + i]; }
    }
  }
  __syncthreads();
  for (int i = tid; i < n; i += 256) {  // rank sort: broadcast reads, no barriers
    u64 ki = k[i];
    u32 rank = 0;
    int j = 0;
    for (; j + 4 <= n; j += 4) {
      rank += (k[j] > ki) ? 1u : 0u;
      rank += (k[j + 1] > ki) ? 1u : 0u;
      rank += (k[j + 2] > ki) ? 1u : 0u;
      rank += (k[j + 3] > ki) ? 1u : 0u;
    }
    for (; j < n; ++j) rank += (k[j] > ki) ? 1u : 0u;
    ks[rank] = ki;
    boxs[rank] = boxu[i];
  }
  __syncthreads();
  if (tid >= 64) return;  // wave 0 continues barrier-free

  float H = (float)dh[0], W = (float)dw[0];
  float loff = (fmaxf(H, W) + 1.0f) * (float)(ci + 1);
  int lane = tid;
  int S = 0;
  for (int base = 0; base < n && S < NDET; base += 64) {
    int i = base + lane;
    bool have = (i < n);
    u64 mykey = 0ull;
    float4 Bb = make_float4(0.f, 0.f, 0.f, 0.f);
    float aB = 0.f;
    if (have) {
      mykey = ks[i];
      float4 raw = boxs[i];
      Bb = make_float4(raw.x + loff, raw.y + loff, raw.z + loff, raw.w + loff);
      aB = (Bb.z - Bb.x) * (Bb.w - Bb.y);
    }
    bool alive = have;
    for (int s = 0; s < S; ++s) {  // independent LDS reads, pipelined
      float4 A = s_sb[s];
      float aA = s_sa[s];
      float ix1 = fmaxf(A.x, Bb.x), iy1 = fmaxf(A.y, Bb.y);
      float ix2 = fminf(A.z, Bb.z), iy2 = fminf(A.w, Bb.w);
      float inter = fmaxf(ix2 - ix1, 0.0f) * fmaxf(iy2 - iy1, 0.0f);
      float iou = inter / fmaxf(aA + aB - inter, 1e-9f);
      if (alive && iou > 0.5f) alive = false;
    }
    u64 mask = __ballot(alive);
    while (mask && S < NDET) {
      int j = __builtin_ctzll(mask);               // wave-uniform
      int js = __builtin_amdgcn_readfirstlane(j);  // pin scalar
      float Ax = rdlane(Bb.x, js), Ay = rdlane(Bb.y, js);
      float Az = rdlane(Bb.z, js), Aw = rdlane(Bb.w, js);
      float aA = rdlane(aB, js);
      if (lane == js) {
        s_sb[S] = Bb; s_sa[S] = aB; s_sk[S] = mykey; s_sid[S] = (u32)i;
      }
      float ix1 = fmaxf(Ax, Bb.x), iy1 = fmaxf(Ay, Bb.y);
      float ix2 = fminf(Az, Bb.z), iy2 = fminf(Aw, Bb.w);
      float inter = fmaxf(ix2 - ix1, 0.0f) * fmaxf(iy2 - iy1, 0.0f);
      float iou = inter / fmaxf(aA + aB - inter, 1e-9f);
      if (alive && iou > 0.5f) alive = false;  // selected lane leaves (IoU=1)
      ++S;
      mask = __ballot(alive);
    }
  }
  for (int i2 = lane; i2 < NDET; i2 += 64) {  // fixed slots, zero-padded
    if (i2 < S) {
      outk[i2] = s_sk[i2];
      outb[i2] = boxs[s_sid[i2]];
    } else {
      outk[i2] = 0ull;
    }
  }
}

// Per-image exact top-NDET over the fixed 9000 survivor slots (key==0 =
// empty, never selectable). Register-resident bisection on (0.05,1] bits
// for the 100th-largest score T; compact >T plus ==T ties; wave-0 rank
// sort (keys unique) into the 100 outputs.
__global__ __launch_bounds__(256) void k_top(const u64* __restrict__ skey,
    const float4* __restrict__ sbox, float* out) {
  __shared__ u32 ssc[SURVCAP];
  __shared__ u32 s_red[4];
  __shared__ u32 s_cnt[2];
  __shared__ u64 fk[FKCAP];
  __shared__ u32 fs[FKCAP];
  __shared__ u64 okey[NDET];
  __shared__ u32 osrc[NDET];

  int b = blockIdx.x;
  int tid = threadIdx.x;
  const u64* kb = skey + (size_t)b * SURVCAP;

  u32 sc[VPT];
#pragma unroll
  for (int v = 0; v < VPT; ++v) {
    u32 j = (u32)tid + (u32)v * 256u;
    u32 s = 0u;
    if (j < NSFIX) s = (u32)(kb[j] >> 22);
    sc[v] = s;
    ssc[j] = s;
  }
  if (tid == 0) { s_cnt[0] = 0; s_cnt[1] = 0; }
  __syncthreads();

  // minimal x with count(s > x) < NDET; scores in (0.05, 1]
  u32 lo = 0x3D4CCCCEu, hi = 0x3F800001u;
  while (lo < hi) {
    u32 mid = lo + ((hi - lo) >> 1);
    u32 c = 0;
#pragma unroll
    for (int v = 0; v < VPT; ++v) c += (sc[v] > mid) ? 1u : 0u;
    for (int o = 32; o; o >>= 1) c += __shfl_xor(c, o);
    if ((tid & 63) == 0) s_red[tid >> 6] = c;
    __syncthreads();
    u32 totc = s_red[0] + s_red[1] + s_red[2] + s_red[3];
    __syncthreads();
    if (totc < NDET) hi = mid; else lo = mid + 1;
  }
  u32 T = lo;
  __syncthreads();

  for (u32 j = tid; j < NSFIX; j += 256) {
    if (ssc[j] > T) {
      u32 p = atomicAdd(&s_cnt[0], 1u);
      if (p < FKCAP) { fk[p] = kb[j]; fs[p] = j; }
    }
  }
  __syncthreads();
  if (tid == 0) s_cnt[1] = s_cnt[0];
  __syncthreads();
  for (u32 j = tid; j < NSFIX; j += 256) {  // ==T ties; order fixed by rank sort
    if (ssc[j] == T) {
      u32 p = atomicAdd(&s_cnt[1], 1u);
      if (p < FKCAP) { fk[p] = kb[j]; fs[p] = j; }
    }
  }
  __syncthreads();
  u32 tot = s_cnt[1];
  if (tot > FKCAP) tot = FKCAP;
  if (tid >= 64) return;  // wave 0 finishes barrier-free

  for (int i = tid; i < NDET; i += 64) okey[i] = 0ull;
  for (int i = tid; i < (int)tot; i += 64) {  // rank sort (keys unique)
    u64 ki = fk[i];
    u32 rank = 0;
    for (int j = 0; j < (int)tot; ++j) rank += (fk[j] > ki) ? 1u : 0u;
    if (rank < NDET) { okey[rank] = ki; osrc[rank] = fs[i]; }
  }
  // boxes[3200] | scores[800] | labels[800] | keep[800]
  for (int i = tid; i < NDET; i += 64) {
    u64 key = okey[i];
    float b0 = 0.f, b1 = 0.f, b2 = 0.f, b3 = 0.f, sc2 = 0.f, lb = 0.f, kp = 0.f;
    if (key) {
      float4 bx = sbox[(size_t)b * SURVCAP + osrc[i]];
      b0 = bx.x; b1 = bx.y; b2 = bx.z; b3 = bx.w;
      sc2 = __uint_as_float((u32)(key >> 22));
      u32 orig = 0x3FFFFFu - (u32)(key & 0x3FFFFFu);
      lb = (float)(orig % NCLS + 1u);
      kp = 1.0f;
    }
    float* ob = out + ((size_t)b * NDET + i) * 4;
    ob[0] = b0; ob[1] = b1; ob[2] = b2; ob[3] = b3;
    out[NB * NDET * 4 + b * NDET + i] = sc2;
    out[NB * NDET * 5 + b * NDET + i] = lb;
    out[NB * NDET * 6 + b * NDET + i] = kp;
  }
}

// ---------------------------------------------------------------- launch ----
extern "C" void kernel_launch(void* const* d_in, const int* in_sizes, int n_in,
                              void* d_out, int out_size, void* d_ws, size_t ws_size,
                              hipStream_t stream) {
  const float* logits = (const float*)d_in[0];
  const float* boxreg = (const float*)d_in[1];
  const float* props  = (const float*)d_in[2];
  const int* dh = (const int*)d_in[3];
  const int* dw = (const int*)d_in[4];
  float* out = (float*)d_out;

  char* ws = (char*)d_ws;
  u32* cnt_g = (u32*)ws;                                      // 8*64*90 u32 = 180 KiB
  char* p0 = ws + (((size_t)NB * CHUNKS * NCLS * 4 + 255) & ~(size_t)255);
  u64* bins_key = (u64*)p0;                                   // 8*64*90*63*8  = 23.2 MB
  char* p1 = p0 + (size_t)NB * CHUNKS * NCLS * CCAP * 8;
  float4* bins_box = (float4*)p1;                             // 8*64*90*63*16 = 46.4 MB
  char* p2 = p1 + (size_t)NB * CHUNKS * NCLS * CCAP * 16;
  u64* skey = (u64*)p2;                                       // 8*9216*8 = 590 KB
  float4* sbox = (float4*)(p2 + (size_t)NB * SURVCAP * 8);    // 8*9216*16 = 1.18 MB
  (void)ws_size;

  k_score<<<NB * CHUNKS, 1024, 0, stream>>>(logits, boxreg, props, dh, dw,
                                            cnt_g, bins_key, bins_box);
  k_nms_class<<<NB * NCLS, 256, 0, stream>>>(cnt_g, bins_key, bins_box,
                                             skey, sbox, dh, dw);
  k_top<<<NB, 256, 0, stream>>>(skey, sbox, out);
}